// Round 2
// baseline (357.477 us; speedup 1.0000x reference)
//
#include <hip/hip_runtime.h>
#include <math.h>

typedef __bf16 bf16x8 __attribute__((ext_vector_type(8)));
typedef float  f32x4  __attribute__((ext_vector_type(4)));

// ---------- helpers ----------
__device__ __forceinline__ unsigned short f2bf(float f) {
    union { float f; unsigned int u; } v; v.f = f;
    unsigned int u = v.u;
    unsigned int r = (u + 0x7FFFu + ((u >> 16) & 1u)) >> 16;   // RNE, finite inputs only
    return (unsigned short)r;
}

__device__ __forceinline__ void g2l16(const void* g, void* l) {
    // async global->LDS, 16B per lane; LDS dest = wave-uniform base + lane*16
    __builtin_amdgcn_global_load_lds(
        (__attribute__((address_space(1))) void*)g,
        (__attribute__((address_space(3))) void*)l,
        16, 0, 0);
}

// ---------- quantization prep ----------
__global__ void init_slots(unsigned int* slots) {
    if (threadIdx.x < 3) slots[threadIdx.x] = 0u;
}

__global__ void absmax_kernel(const float* __restrict__ w, int n, unsigned int* slot) {
    float m = 0.f;
    for (int i = blockIdx.x * blockDim.x + threadIdx.x; i < n; i += gridDim.x * blockDim.x)
        m = fmaxf(m, fabsf(w[i]));
    #pragma unroll
    for (int off = 32; off; off >>= 1)
        m = fmaxf(m, __shfl_down(m, off));
    __shared__ float sm[4];
    int lane = threadIdx.x & 63, wv = threadIdx.x >> 6;
    if (lane == 0) sm[wv] = m;
    __syncthreads();
    if (threadIdx.x == 0) {
        float mm = fmaxf(fmaxf(sm[0], sm[1]), fmaxf(sm[2], sm[3]));
        atomicMax(slot, __float_as_uint(mm));
    }
}

// W stored [N,K] row-major; output bf16 bits of clip(rint(W/s),-127,127)*s*post
__global__ void quant_w(const float* __restrict__ w, unsigned short* __restrict__ out, int n,
                        const unsigned int* __restrict__ slot, float post) {
    float s = __uint_as_float(*slot) / 127.0f;
    for (int i = blockIdx.x * blockDim.x + threadIdx.x; i < n; i += gridDim.x * blockDim.x) {
        float q = rintf(w[i] / s);
        q = fminf(fmaxf(q, -127.f), 127.f);
        out[i] = f2bf(q * s * post);
    }
}

__global__ void quant_b(const float* __restrict__ b1, const float* __restrict__ b2,
                        const float* __restrict__ b3,
                        float* __restrict__ o1, float* __restrict__ o2, float* __restrict__ o3,
                        const unsigned int* __restrict__ slots) {
    const float s_in = (float)(1.0 / 12000.0);
    float ws1 = __uint_as_float(slots[0]) / 127.0f;
    float ws2 = __uint_as_float(slots[1]) / 127.0f;
    float ws3 = __uint_as_float(slots[2]) / 127.0f;
    float sb1 = s_in * ws1;        // = s1
    float sb2 = sb1 * ws2;         // = s2
    float sb3 = sb2 * ws3;
    int i = blockIdx.x * blockDim.x + threadIdx.x;
    if (i < 1024) o1[i] = fminf(fmaxf(rintf(b1[i] / sb1), -128.f), 127.f) * sb1;
    if (i < 1024) o2[i] = fminf(fmaxf(rintf(b2[i] / sb2), -128.f), 127.f) * sb2;
    if (i < 128)  o3[i] = fminf(fmaxf(rintf(b3[i] / sb3), -128.f), 127.f) * sb3;
}

__global__ void cvt_bf16(const float* __restrict__ in, unsigned short* __restrict__ out, int n) {
    int i = (blockIdx.x * blockDim.x + threadIdx.x) * 4;
    int stride = gridDim.x * blockDim.x * 4;
    for (; i < n; i += stride) {
        float4 v = *(const float4*)(in + i);
        ushort4 o;
        o.x = f2bf(v.x); o.y = f2bf(v.y); o.z = f2bf(v.z); o.w = f2bf(v.w);
        *(ushort4*)(out + i) = o;
    }
}

// ---------- GEMM: C[M,N] = A[M,K] @ W[N,K]^T (+bias), m97-style 128x128 tile ----------
// MODE 0: relu -> bf16 out ; MODE 1: fp32 out (no relu)
template <int MODE>
__global__ __launch_bounds__(256)
void gemm_bt(const unsigned short* __restrict__ A,   // [M,K] bf16 bits
             const unsigned short* __restrict__ Wt,  // [N,K] bf16 bits
             const float* __restrict__ bias,         // [N]
             void* __restrict__ out, int M, int N, int K) {
    __shared__ short lA[128 * 64];
    __shared__ short lB[128 * 64];
    const int tid  = threadIdx.x;
    const int wv   = tid >> 6, lane = tid & 63;
    const int wr   = wv >> 1,  wc   = wv & 1;       // 2x2 waves -> 64x64 each
    const int l15  = lane & 15, l4  = lane >> 4;
    const size_t rowA0 = (size_t)blockIdx.y * 128;
    const size_t rowB0 = (size_t)blockIdx.x * 128;
    const unsigned short* Ab = A  + rowA0 * K;
    const unsigned short* Bb = Wt + rowB0 * K;
    const int arow = tid >> 3;         // 0..31
    const int acol = (tid & 7) * 8;    // 0..56

    f32x4 acc[4][4];
    #pragma unroll
    for (int i = 0; i < 4; ++i)
        #pragma unroll
        for (int j = 0; j < 4; ++j)
            acc[i][j] = f32x4{0.f, 0.f, 0.f, 0.f};

    for (int k0 = 0; k0 < K; k0 += 64) {
        #pragma unroll
        for (int c = 0; c < 4; ++c) {
            g2l16(Ab + (size_t)(c * 32 + arow) * K + k0 + acol, (char*)lA + c * 4096 + tid * 16);
            g2l16(Bb + (size_t)(c * 32 + arow) * K + k0 + acol, (char*)lB + c * 4096 + tid * 16);
        }
        __syncthreads();   // drains vmcnt then barrier
        #pragma unroll
        for (int kk = 0; kk < 2; ++kk) {
            bf16x8 af[4], bfr[4];
            #pragma unroll
            for (int i = 0; i < 4; ++i)
                af[i] = *(const bf16x8*)(lA + (wr * 64 + i * 16 + l15) * 64 + kk * 32 + l4 * 8);
            #pragma unroll
            for (int j = 0; j < 4; ++j)
                bfr[j] = *(const bf16x8*)(lB + (wc * 64 + j * 16 + l15) * 64 + kk * 32 + l4 * 8);
            #pragma unroll
            for (int i = 0; i < 4; ++i)
                #pragma unroll
                for (int j = 0; j < 4; ++j)
                    acc[i][j] = __builtin_amdgcn_mfma_f32_16x16x32_bf16(af[i], bfr[j], acc[i][j], 0, 0, 0);
        }
        __syncthreads();
    }

    const int gr0 = (int)rowA0 + wr * 64;
    const int gc0 = (int)rowB0 + wc * 64;
    #pragma unroll
    for (int i = 0; i < 4; ++i) {
        #pragma unroll
        for (int j = 0; j < 4; ++j) {
            int col = gc0 + j * 16 + l15;
            float bv = bias[col];
            #pragma unroll
            for (int r = 0; r < 4; ++r) {
                int row = gr0 + i * 16 + l4 * 4 + r;   // C/D: col=lane&15, row=quad*4+reg
                float v = acc[i][j][r] + bv;
                if (MODE == 0) {
                    v = fmaxf(v, 0.f);
                    ((unsigned short*)out)[(size_t)row * N + col] = f2bf(v);
                } else {
                    ((float*)out)[(size_t)row * N + col] = v;
                }
            }
        }
    }
}

// ---------- final: rsample + tanh-squash + logp (fp32 outputs) ----------
__global__ void finale(const float* __restrict__ net, const float* __restrict__ eps,
                       float* __restrict__ act_out, float* __restrict__ logp_out) {
    int b = blockIdx.x * 4 + (threadIdx.x >> 6);
    int j = threadIdx.x & 63;
    float mu = net[(size_t)b * 128 + j];
    float ls = net[(size_t)b * 128 + 64 + j];
    ls = fminf(fmaxf(ls, -20.f), 2.f);
    float sd = expf(ls);
    float e  = eps[(size_t)b * 64 + j];
    float pi = fmaf(sd, e, mu);
    act_out[(size_t)b * 64 + j] = tanhf(pi);
    float lp = -0.5f * e * e - ls - 0.91893853320467274178f;   // -0.5*log(2*pi)
    float xn = -2.f * pi;
    float sp = fmaxf(xn, 0.f) + log1pf(expf(-fabsf(xn)));      // stable softplus(-2*pi)
    lp -= 2.f * (0.69314718055994530942f - pi - sp);
    #pragma unroll
    for (int off = 32; off; off >>= 1) lp += __shfl_down(lp, off);
    if (j == 0) logp_out[b] = lp;
}

// ---------- launch ----------
extern "C" void kernel_launch(void* const* d_in, const int* in_sizes, int n_in,
                              void* d_out, int out_size, void* d_ws, size_t ws_size,
                              hipStream_t stream) {
    const float* obs = (const float*)d_in[0];
    const float* eps = (const float*)d_in[1];
    const float* W1  = (const float*)d_in[2];
    const float* b1  = (const float*)d_in[3];
    const float* W2  = (const float*)d_in[4];
    const float* b2  = (const float*)d_in[5];
    const float* W3  = (const float*)d_in[6];
    const float* b3  = (const float*)d_in[7];
    const int B = 32768, OBS = 512, H1 = 1024, H2 = 1024, ACT = 64;

    char* ws = (char*)d_ws;
    // x (32 MB) is dead after GEMM1; net (16 MB) aliases it.
    unsigned short* x   = (unsigned short*)(ws);                 // 32 MB  [B*OBS bf16]
    float*          net = (float*)(ws);                          // 16 MB  [B*128 f32] (after GEMM1)
    unsigned short* h1  = (unsigned short*)(ws + 33554432);      // 64 MB  [B*H1 bf16]
    unsigned short* h2  = (unsigned short*)(ws + 100663296);     // 64 MB  [B*H2 bf16]
    unsigned short* W1s = (unsigned short*)(ws + 167772160);     // 1 MB
    unsigned short* W2s = (unsigned short*)(ws + 168820736);     // 2 MB
    unsigned short* W3s = (unsigned short*)(ws + 170917888);     // 256 KB
    float*          b1q = (float*)(ws + 171180032);
    float*          b2q = (float*)(ws + 171184128);
    float*          b3q = (float*)(ws + 171188224);
    unsigned int*   slots = (unsigned int*)(ws + 171188736);

    init_slots<<<1, 64, 0, stream>>>(slots);
    absmax_kernel<<<256, 256, 0, stream>>>(W1, H1 * OBS, slots + 0);
    absmax_kernel<<<256, 256, 0, stream>>>(W2, H2 * H1, slots + 1);
    absmax_kernel<<<128, 256, 0, stream>>>(W3, 2 * ACT * H2, slots + 2);

    const float c = (float)((1.0 / 12000.0) * (1.0 / 12000.0)); // fold input scaling into W1
    quant_w<<<512, 256, 0, stream>>>(W1, W1s, H1 * OBS, slots + 0, c);
    quant_w<<<1024, 256, 0, stream>>>(W2, W2s, H2 * H1, slots + 1, 1.0f);
    quant_w<<<128, 256, 0, stream>>>(W3, W3s, 2 * ACT * H2, slots + 2, 1.0f);
    quant_b<<<4, 256, 0, stream>>>(b1, b2, b3, b1q, b2q, b3q, slots);

    cvt_bf16<<<2048, 256, 0, stream>>>(obs, x, B * OBS);

    gemm_bt<0><<<dim3(H1 / 128, B / 128), 256, 0, stream>>>(x,  W1s, b1q, h1,  B, H1,      OBS);
    gemm_bt<0><<<dim3(H2 / 128, B / 128), 256, 0, stream>>>(h1, W2s, b2q, h2,  B, H2,      H1);
    gemm_bt<1><<<dim3(1,        B / 128), 256, 0, stream>>>(h2, W3s, b3q, net, B, 2 * ACT, H2);

    float* act_out  = (float*)d_out;
    float* logp_out = act_out + (size_t)B * ACT;
    finale<<<B / 4, 256, 0, stream>>>(net, eps, act_out, logp_out);
}

// Round 3
// 318.193 us; speedup vs baseline: 1.1235x; 1.1235x over previous
//
#include <hip/hip_runtime.h>
#include <math.h>

typedef __bf16 bf16x8 __attribute__((ext_vector_type(8)));
typedef float  f32x4  __attribute__((ext_vector_type(4)));

// ---------- helpers ----------
__device__ __forceinline__ unsigned short f2bf(float f) {
    union { float f; unsigned int u; } v; v.f = f;
    unsigned int u = v.u;
    unsigned int r = (u + 0x7FFFu + ((u >> 16) & 1u)) >> 16;   // RNE, finite inputs only
    return (unsigned short)r;
}

__device__ __forceinline__ void g2l16(const void* g, void* l) {
    // async global->LDS, 16B per lane; LDS dest = wave-uniform base + lane*16
    __builtin_amdgcn_global_load_lds(
        (__attribute__((address_space(1))) void*)g,
        (__attribute__((address_space(3))) void*)l,
        16, 0, 0);
}

// ---------- quant prep: stage 1 — per-block absmax partials (poison-safe, no init) ----------
// blocks 0..127 -> W1 (524288), 128..255 -> W2 (1048576), 256..287 -> W3 (131072)
__global__ void wprep1(const float* __restrict__ W1, const float* __restrict__ W2,
                       const float* __restrict__ W3, float* __restrict__ pmax) {
    int blk = blockIdx.x;
    const float* w; int n, b, nb;
    if (blk < 128)      { w = W1; n = 524288;  b = blk;       nb = 128; }
    else if (blk < 256) { w = W2; n = 1048576; b = blk - 128; nb = 128; }
    else                { w = W3; n = 131072;  b = blk - 256; nb = 32;  }
    float m = 0.f;
    for (int i = b * 256 + threadIdx.x; i < n; i += nb * 256)
        m = fmaxf(m, fabsf(w[i]));
    #pragma unroll
    for (int off = 32; off; off >>= 1)
        m = fmaxf(m, __shfl_down(m, off));
    __shared__ float sm[4];
    int lane = threadIdx.x & 63, wv = threadIdx.x >> 6;
    if (lane == 0) sm[wv] = m;
    __syncthreads();
    if (threadIdx.x == 0)
        pmax[blockIdx.x] = fmaxf(fmaxf(sm[0], sm[1]), fmaxf(sm[2], sm[3]));
}

// ---------- stage 2: reduce partials -> scales; quantize biases ----------
__global__ void wprep2(const float* __restrict__ pmax,
                       const float* __restrict__ b1, const float* __restrict__ b2,
                       const float* __restrict__ b3,
                       float* __restrict__ scales,
                       float* __restrict__ b1q, float* __restrict__ b2q, float* __restrict__ b3q) {
    __shared__ float sred[3][4];
    __shared__ float ssc[3];
    int tid = threadIdx.x, lane = tid & 63, wv = tid >> 6;
    float m0 = (tid < 128) ? pmax[tid] : 0.f;
    float m1 = (tid < 128) ? pmax[128 + tid] : 0.f;
    float m2 = (tid < 32)  ? pmax[256 + tid] : 0.f;
    #pragma unroll
    for (int off = 32; off; off >>= 1) {
        m0 = fmaxf(m0, __shfl_down(m0, off));
        m1 = fmaxf(m1, __shfl_down(m1, off));
        m2 = fmaxf(m2, __shfl_down(m2, off));
    }
    if (lane == 0) { sred[0][wv] = m0; sred[1][wv] = m1; sred[2][wv] = m2; }
    __syncthreads();
    if (tid < 3) {
        float mm = fmaxf(fmaxf(sred[tid][0], sred[tid][1]), fmaxf(sred[tid][2], sred[tid][3]));
        float s = mm / 127.0f;
        scales[tid] = s; ssc[tid] = s;
    }
    __syncthreads();
    const float s_in = (float)(1.0 / 12000.0);
    float sb1 = s_in * ssc[0];
    float sb2 = sb1 * ssc[1];
    float sb3 = sb2 * ssc[2];
    for (int i = tid; i < 1024; i += 256) {
        b1q[i] = fminf(fmaxf(rintf(b1[i] / sb1), -128.f), 127.f) * sb1;
        b2q[i] = fminf(fmaxf(rintf(b2[i] / sb2), -128.f), 127.f) * sb2;
    }
    if (tid < 128) b3q[tid] = fminf(fmaxf(rintf(b3[tid] / sb3), -128.f), 127.f) * sb3;
}

// ---------- quantize all weights (bf16 dequantized; W1 gets s_in^2 folded in) ----------
// blocks 0..255 -> W1, 256..767 -> W2, 768..831 -> W3 ; 2048 elems/block
__global__ void quant_w_all(const float* __restrict__ W1, const float* __restrict__ W2,
                            const float* __restrict__ W3,
                            unsigned short* __restrict__ W1s, unsigned short* __restrict__ W2s,
                            unsigned short* __restrict__ W3s,
                            const float* __restrict__ scales) {
    const float c = (float)((1.0 / 12000.0) * (1.0 / 12000.0));
    int b = blockIdx.x;
    const float* w; unsigned short* o; float s; float post; int base;
    if (b < 256)      { w = W1; o = W1s; s = scales[0]; post = c;   base = b * 2048; }
    else if (b < 768) { w = W2; o = W2s; s = scales[1]; post = 1.f; base = (b - 256) * 2048; }
    else              { w = W3; o = W3s; s = scales[2]; post = 1.f; base = (b - 768) * 2048; }
    for (int i = base + threadIdx.x; i < base + 2048; i += 256) {
        float q = rintf(w[i] / s);
        q = fminf(fmaxf(q, -127.f), 127.f);
        o[i] = f2bf(q * s * post);
    }
}

__global__ void cvt_bf16(const float* __restrict__ in, unsigned short* __restrict__ out, int n) {
    int i = (blockIdx.x * blockDim.x + threadIdx.x) * 4;
    int stride = gridDim.x * blockDim.x * 4;
    for (; i < n; i += stride) {
        float4 v = *(const float4*)(in + i);
        ushort4 o;
        o.x = f2bf(v.x); o.y = f2bf(v.y); o.z = f2bf(v.z); o.w = f2bf(v.w);
        *(ushort4*)(out + i) = o;
    }
}

// ---------- GEMM: C = relu(A @ Wt^T + bias) -> bf16, 128x128 tile ----------
// XCD swizzle: same-A blocks colocated per XCD (lid%8). XOR swizzle: LDS chunk
// q of row r holds global chunk q^(r&7) (breaks the 16-way b128 bank conflict).
template <int LGX>
__global__ __launch_bounds__(256)
void gemm_bt(const unsigned short* __restrict__ A,   // [M,K] bf16 bits
             const unsigned short* __restrict__ Wt,  // [N,K] bf16 bits
             const float* __restrict__ bias,         // [N]
             unsigned short* __restrict__ out, int N, int K) {
    __shared__ short lA[128 * 64];
    __shared__ short lB[128 * 64];
    const int tid  = threadIdx.x;
    const int wv   = tid >> 6, lane = tid & 63;
    const int wr   = wv >> 1,  wc   = wv & 1;
    const int l15  = lane & 15, l4  = lane >> 4;
    // XCD-aware block swizzle (bijective remap; correctness mapping-independent)
    const int lid  = blockIdx.y * gridDim.x + blockIdx.x;
    const int xcd  = lid & 7;
    const int s    = lid >> 3;
    const int mblk = (s >> LGX) * 8 + xcd;
    const int nblk = s & ((1 << LGX) - 1);
    const size_t rowA0 = (size_t)mblk * 128;
    const size_t rowB0 = (size_t)nblk * 128;
    const unsigned short* Ab = A  + rowA0 * K;
    const unsigned short* Bb = Wt + rowB0 * K;
    const int arow = tid >> 3;                 // 0..31 (row within 32-row chunk group)
    const int qsw  = (tid & 7) ^ (arow & 7);   // XOR-swizzled source chunk

    f32x4 acc[4][4];
    #pragma unroll
    for (int i = 0; i < 4; ++i)
        #pragma unroll
        for (int j = 0; j < 4; ++j)
            acc[i][j] = f32x4{0.f, 0.f, 0.f, 0.f};

    for (int k0 = 0; k0 < K; k0 += 64) {
        #pragma unroll
        for (int c = 0; c < 4; ++c) {
            g2l16(Ab + (size_t)(c * 32 + arow) * K + k0 + qsw * 8, (char*)lA + c * 4096 + tid * 16);
            g2l16(Bb + (size_t)(c * 32 + arow) * K + k0 + qsw * 8, (char*)lB + c * 4096 + tid * 16);
        }
        __syncthreads();
        #pragma unroll
        for (int kk = 0; kk < 2; ++kk) {
            const int ch = ((kk * 4 + l4) ^ (lane & 7)) * 8;   // de-swizzled LDS chunk offset
            bf16x8 af[4], bfr[4];
            #pragma unroll
            for (int i = 0; i < 4; ++i)
                af[i] = *(const bf16x8*)(lA + (wr * 64 + i * 16 + l15) * 64 + ch);
            #pragma unroll
            for (int j = 0; j < 4; ++j)
                bfr[j] = *(const bf16x8*)(lB + (wc * 64 + j * 16 + l15) * 64 + ch);
            #pragma unroll
            for (int i = 0; i < 4; ++i)
                #pragma unroll
                for (int j = 0; j < 4; ++j)
                    acc[i][j] = __builtin_amdgcn_mfma_f32_16x16x32_bf16(af[i], bfr[j], acc[i][j], 0, 0, 0);
        }
        __syncthreads();
    }

    const int gr0 = (int)rowA0 + wr * 64;
    const int gc0 = (int)rowB0 + wc * 64;
    #pragma unroll
    for (int i = 0; i < 4; ++i) {
        #pragma unroll
        for (int j = 0; j < 4; ++j) {
            int col = gc0 + j * 16 + l15;
            float bv = bias[col];
            #pragma unroll
            for (int r = 0; r < 4; ++r) {
                int row = gr0 + i * 16 + l4 * 4 + r;
                float v = fmaxf(acc[i][j][r] + bv, 0.f);
                out[(size_t)row * N + col] = f2bf(v);
            }
        }
    }
}

// ---------- GEMM3 + finale fused: net = h2 @ W3^T + b3 ; rsample/tanh/logp ----------
// N=128 == tile width, so each block owns 128 complete batch rows.
__global__ __launch_bounds__(256)
void gemm3_fused(const unsigned short* __restrict__ A,   // h2 [B,1024]
                 const unsigned short* __restrict__ Wt,  // W3s [128,1024]
                 const float* __restrict__ bias,         // [128]
                 const float* __restrict__ eps,          // [B,64]
                 float* __restrict__ act_out, float* __restrict__ logp_out, int K) {
    __shared__ short lA[128 * 64];
    __shared__ short lB[128 * 64];
    const int tid  = threadIdx.x;
    const int wv   = tid >> 6, lane = tid & 63;
    const int wr   = wv >> 1,  wc   = wv & 1;
    const int l15  = lane & 15, l4  = lane >> 4;
    const size_t rowA0 = (size_t)blockIdx.x * 128;
    const unsigned short* Ab = A + rowA0 * K;
    const int arow = tid >> 3;
    const int qsw  = (tid & 7) ^ (arow & 7);

    f32x4 acc[4][4];
    #pragma unroll
    for (int i = 0; i < 4; ++i)
        #pragma unroll
        for (int j = 0; j < 4; ++j)
            acc[i][j] = f32x4{0.f, 0.f, 0.f, 0.f};

    for (int k0 = 0; k0 < K; k0 += 64) {
        #pragma unroll
        for (int c = 0; c < 4; ++c) {
            g2l16(Ab + (size_t)(c * 32 + arow) * K + k0 + qsw * 8, (char*)lA + c * 4096 + tid * 16);
            g2l16(Wt + (size_t)(c * 32 + arow) * K + k0 + qsw * 8, (char*)lB + c * 4096 + tid * 16);
        }
        __syncthreads();
        #pragma unroll
        for (int kk = 0; kk < 2; ++kk) {
            const int ch = ((kk * 4 + l4) ^ (lane & 7)) * 8;
            bf16x8 af[4], bfr[4];
            #pragma unroll
            for (int i = 0; i < 4; ++i)
                af[i] = *(const bf16x8*)(lA + (wr * 64 + i * 16 + l15) * 64 + ch);
            #pragma unroll
            for (int j = 0; j < 4; ++j)
                bfr[j] = *(const bf16x8*)(lB + (wc * 64 + j * 16 + l15) * 64 + ch);
            #pragma unroll
            for (int i = 0; i < 4; ++i)
                #pragma unroll
                for (int j = 0; j < 4; ++j)
                    acc[i][j] = __builtin_amdgcn_mfma_f32_16x16x32_bf16(af[i], bfr[j], acc[i][j], 0, 0, 0);
        }
        __syncthreads();
    }

    // Epilogue: cols 0..63 = mu (waves wc=0), 64..127 = log_std (wc=1).
    // Two phases over row halves (wr), routing through lA/lB as float[64*64]
    // with +row index rotation to keep reads ~2-way.
    float* fmu = (float*)lA;
    float* fls = (float*)lB;
    for (int p = 0; p < 2; ++p) {
        __syncthreads();
        if (wr == p) {
            float* dst = wc ? fls : fmu;
            #pragma unroll
            for (int i = 0; i < 4; ++i) {
                #pragma unroll
                for (int j = 0; j < 4; ++j) {
                    int c = j * 16 + l15;                 // 0..63
                    float bv = bias[wc * 64 + c];
                    #pragma unroll
                    for (int r = 0; r < 4; ++r) {
                        int lr = i * 16 + l4 * 4 + r;     // 0..63
                        dst[lr * 64 + ((c + lr) & 63)] = acc[i][j][r] + bv;
                    }
                }
            }
        }
        __syncthreads();
        {
            int r = tid >> 2;                              // 0..63 (local row in phase)
            size_t grow = rowA0 + p * 64 + r;
            float lp = 0.f;
            #pragma unroll
            for (int t = 0; t < 16; ++t) {
                int j = (tid & 3) * 16 + t;                // 0..63
                int rot = (j + r) & 63;
                float mu = fmu[r * 64 + rot];
                float ls = fls[r * 64 + rot];
                ls = fminf(fmaxf(ls, -20.f), 2.f);
                float sd = expf(ls);
                float e  = eps[grow * 64 + j];
                float pi = fmaf(sd, e, mu);
                act_out[grow * 64 + j] = tanhf(pi);
                lp += -0.5f * e * e - ls - 0.91893853320467274178f;
                float xn = -2.f * pi;
                float sp = fmaxf(xn, 0.f) + log1pf(expf(-fabsf(xn)));
                lp -= 2.f * (0.69314718055994530942f - pi - sp);
            }
            lp += __shfl_xor(lp, 1);
            lp += __shfl_xor(lp, 2);
            if ((tid & 3) == 0) logp_out[grow] = lp;
        }
    }
}

// ---------- launch ----------
extern "C" void kernel_launch(void* const* d_in, const int* in_sizes, int n_in,
                              void* d_out, int out_size, void* d_ws, size_t ws_size,
                              hipStream_t stream) {
    const float* obs = (const float*)d_in[0];
    const float* eps = (const float*)d_in[1];
    const float* W1  = (const float*)d_in[2];
    const float* b1  = (const float*)d_in[3];
    const float* W2  = (const float*)d_in[4];
    const float* b2  = (const float*)d_in[5];
    const float* W3  = (const float*)d_in[6];
    const float* b3  = (const float*)d_in[7];
    const int B = 32768, OBS = 512, H1 = 1024, H2 = 1024;

    char* ws = (char*)d_ws;
    unsigned short* x   = (unsigned short*)(ws);                 // 32 MB [B*OBS bf16]
    unsigned short* h1  = (unsigned short*)(ws + 33554432);      // 64 MB
    unsigned short* h2  = (unsigned short*)(ws + 100663296);     // 64 MB
    unsigned short* W1s = (unsigned short*)(ws + 167772160);     // 1 MB
    unsigned short* W2s = (unsigned short*)(ws + 168820736);     // 2 MB
    unsigned short* W3s = (unsigned short*)(ws + 170917888);     // 256 KB
    float*          b1q = (float*)(ws + 171180032);
    float*          b2q = (float*)(ws + 171184128);
    float*          b3q = (float*)(ws + 171188224);
    float*          scales = (float*)(ws + 171188736);
    float*          pmax   = (float*)(ws + 171189248);           // 288 floats

    wprep1<<<288, 256, 0, stream>>>(W1, W2, W3, pmax);
    wprep2<<<1, 256, 0, stream>>>(pmax, b1, b2, b3, scales, b1q, b2q, b3q);
    quant_w_all<<<832, 256, 0, stream>>>(W1, W2, W3, W1s, W2s, W3s, scales);
    cvt_bf16<<<2048, 256, 0, stream>>>(obs, x, B * OBS);

    gemm_bt<3><<<dim3(8, 256), 256, 0, stream>>>(x,  W1s, b1q, h1, H1, OBS);
    gemm_bt<3><<<dim3(8, 256), 256, 0, stream>>>(h1, W2s, b2q, h2, H2, H1);

    float* act_out  = (float*)d_out;
    float* logp_out = act_out + (size_t)B * 64;
    gemm3_fused<<<256, 256, 0, stream>>>(h2, W3s, b3q, eps, act_out, logp_out, H2);
}

// Round 4
// 278.441 us; speedup vs baseline: 1.2839x; 1.1428x over previous
//
#include <hip/hip_runtime.h>
#include <math.h>

typedef __bf16 bf16x8 __attribute__((ext_vector_type(8)));
typedef float  f32x4  __attribute__((ext_vector_type(4)));

// ---------- helpers ----------
__device__ __forceinline__ unsigned short f2bf(float f) {
    union { float f; unsigned int u; } v; v.f = f;
    unsigned int u = v.u;
    unsigned int r = (u + 0x7FFFu + ((u >> 16) & 1u)) >> 16;   // RNE, finite inputs only
    return (unsigned short)r;
}

__device__ __forceinline__ void g2l16(const void* g, void* l) {
    __builtin_amdgcn_global_load_lds(
        (__attribute__((address_space(1))) void*)g,
        (__attribute__((address_space(3))) void*)l,
        16, 0, 0);
}

// ---------- quant prep: stage 1 — per-block absmax partials ----------
__global__ void wprep1(const float* __restrict__ W1, const float* __restrict__ W2,
                       const float* __restrict__ W3, float* __restrict__ pmax) {
    int blk = blockIdx.x;
    const float* w; int n, b, nb;
    if (blk < 128)      { w = W1; n = 524288;  b = blk;       nb = 128; }
    else if (blk < 256) { w = W2; n = 1048576; b = blk - 128; nb = 128; }
    else                { w = W3; n = 131072;  b = blk - 256; nb = 32;  }
    float m = 0.f;
    for (int i = b * 256 + threadIdx.x; i < n; i += nb * 256)
        m = fmaxf(m, fabsf(w[i]));
    #pragma unroll
    for (int off = 32; off; off >>= 1)
        m = fmaxf(m, __shfl_down(m, off));
    __shared__ float sm[4];
    int lane = threadIdx.x & 63, wv = threadIdx.x >> 6;
    if (lane == 0) sm[wv] = m;
    __syncthreads();
    if (threadIdx.x == 0)
        pmax[blockIdx.x] = fmaxf(fmaxf(sm[0], sm[1]), fmaxf(sm[2], sm[3]));
}

// ---------- stage 2: reduce partials -> scales; quantize biases ----------
__global__ void wprep2(const float* __restrict__ pmax,
                       const float* __restrict__ b1, const float* __restrict__ b2,
                       const float* __restrict__ b3,
                       float* __restrict__ scales,
                       float* __restrict__ b1q, float* __restrict__ b2q, float* __restrict__ b3q) {
    __shared__ float sred[3][4];
    __shared__ float ssc[3];
    int tid = threadIdx.x, lane = tid & 63, wv = tid >> 6;
    float m0 = (tid < 128) ? pmax[tid] : 0.f;
    float m1 = (tid < 128) ? pmax[128 + tid] : 0.f;
    float m2 = (tid < 32)  ? pmax[256 + tid] : 0.f;
    #pragma unroll
    for (int off = 32; off; off >>= 1) {
        m0 = fmaxf(m0, __shfl_down(m0, off));
        m1 = fmaxf(m1, __shfl_down(m1, off));
        m2 = fmaxf(m2, __shfl_down(m2, off));
    }
    if (lane == 0) { sred[0][wv] = m0; sred[1][wv] = m1; sred[2][wv] = m2; }
    __syncthreads();
    if (tid < 3) {
        float mm = fmaxf(fmaxf(sred[tid][0], sred[tid][1]), fmaxf(sred[tid][2], sred[tid][3]));
        float s = mm / 127.0f;
        scales[tid] = s; ssc[tid] = s;
    }
    __syncthreads();
    const float s_in = (float)(1.0 / 12000.0);
    float sb1 = s_in * ssc[0];
    float sb2 = sb1 * ssc[1];
    float sb3 = sb2 * ssc[2];
    for (int i = tid; i < 1024; i += 256) {
        b1q[i] = fminf(fmaxf(rintf(b1[i] / sb1), -128.f), 127.f) * sb1;
        b2q[i] = fminf(fmaxf(rintf(b2[i] / sb2), -128.f), 127.f) * sb2;
    }
    if (tid < 128) b3q[tid] = fminf(fmaxf(rintf(b3[tid] / sb3), -128.f), 127.f) * sb3;
}

// ---------- quantize all weights ----------
__global__ void quant_w_all(const float* __restrict__ W1, const float* __restrict__ W2,
                            const float* __restrict__ W3,
                            unsigned short* __restrict__ W1s, unsigned short* __restrict__ W2s,
                            unsigned short* __restrict__ W3s,
                            const float* __restrict__ scales) {
    const float c = (float)((1.0 / 12000.0) * (1.0 / 12000.0));
    int b = blockIdx.x;
    const float* w; unsigned short* o; float s; float post; int base;
    if (b < 256)      { w = W1; o = W1s; s = scales[0]; post = c;   base = b * 2048; }
    else if (b < 768) { w = W2; o = W2s; s = scales[1]; post = 1.f; base = (b - 256) * 2048; }
    else              { w = W3; o = W3s; s = scales[2]; post = 1.f; base = (b - 768) * 2048; }
    for (int i = base + threadIdx.x; i < base + 2048; i += 256) {
        float q = rintf(w[i] / s);
        q = fminf(fmaxf(q, -127.f), 127.f);
        o[i] = f2bf(q * s * post);
    }
}

__global__ void cvt_bf16(const float* __restrict__ in, unsigned short* __restrict__ out, int n) {
    int i = (blockIdx.x * blockDim.x + threadIdx.x) * 4;
    int stride = gridDim.x * blockDim.x * 4;
    for (; i < n; i += stride) {
        float4 v = *(const float4*)(in + i);
        ushort4 o;
        o.x = f2bf(v.x); o.y = f2bf(v.y); o.z = f2bf(v.z); o.w = f2bf(v.w);
        *(ushort4*)(out + i) = o;
    }
}

// ---------- big-tile GEMM: C = relu(A @ Wt^T + bias) -> bf16 ----------
// Block tile 256(M) x 128(N), BK=64. 4 waves, wave tile 128x64 (acc 8x4).
// LDS-port arithmetic: 384 B read / MFMA (A 4x, B 8x reuse) vs 512 B at 64x64
// wave tiles -> port ceiling rises ~60% -> ~80% MfmaUtil.
template <int LGX>
__global__ __launch_bounds__(256, 2)
void gemm_big(const unsigned short* __restrict__ A,   // [M,K] bf16 bits
              const unsigned short* __restrict__ Wt,  // [N,K] bf16 bits
              const float* __restrict__ bias,         // [N]
              unsigned short* __restrict__ out, int N, int K) {
    __shared__ short lA[256 * 64];   // 32 KB
    __shared__ short lB[128 * 64];   // 16 KB
    const int tid  = threadIdx.x;
    const int wv   = tid >> 6, lane = tid & 63;
    const int wr   = wv >> 1,  wc   = wv & 1;     // wave: 128 rows x 64 cols
    const int l15  = lane & 15, l4  = lane >> 4;
    // XCD-aware swizzle: 8 consecutive n-blocks of one m-strip share an XCD
    const int lid  = blockIdx.y * gridDim.x + blockIdx.x;
    const int xcd  = lid & 7;
    const int s    = lid >> 3;
    const int mblk = (s >> LGX) * 8 + xcd;
    const int nblk = s & ((1 << LGX) - 1);
    const size_t rowA0 = (size_t)mblk * 256;
    const size_t rowB0 = (size_t)nblk * 128;
    const unsigned short* Ab = A  + rowA0 * K;
    const unsigned short* Bb = Wt + rowB0 * K;
    const int arow = tid >> 3;                 // 0..31
    const int qsw  = (tid & 7) ^ (arow & 7);   // XOR-swizzled source chunk

    f32x4 acc[8][4];
    #pragma unroll
    for (int i = 0; i < 8; ++i)
        #pragma unroll
        for (int j = 0; j < 4; ++j)
            acc[i][j] = f32x4{0.f, 0.f, 0.f, 0.f};

    for (int k0 = 0; k0 < K; k0 += 64) {
        #pragma unroll
        for (int c = 0; c < 8; ++c)
            g2l16(Ab + (size_t)(c * 32 + arow) * K + k0 + qsw * 8, (char*)lA + c * 4096 + tid * 16);
        #pragma unroll
        for (int c = 0; c < 4; ++c)
            g2l16(Bb + (size_t)(c * 32 + arow) * K + k0 + qsw * 8, (char*)lB + c * 4096 + tid * 16);
        __syncthreads();
        #pragma unroll
        for (int kk = 0; kk < 2; ++kk) {
            const int ch = ((kk * 4 + l4) ^ (lane & 7)) * 8;   // de-swizzled chunk
            bf16x8 bfr[4];
            #pragma unroll
            for (int j = 0; j < 4; ++j)
                bfr[j] = *(const bf16x8*)(lB + (wc * 64 + j * 16 + l15) * 64 + ch);
            #pragma unroll
            for (int i = 0; i < 8; ++i) {
                bf16x8 af = *(const bf16x8*)(lA + (wr * 128 + i * 16 + l15) * 64 + ch);
                #pragma unroll
                for (int j = 0; j < 4; ++j)
                    acc[i][j] = __builtin_amdgcn_mfma_f32_16x16x32_bf16(af, bfr[j], acc[i][j], 0, 0, 0);
            }
        }
        __syncthreads();
    }

    const int gr0 = (int)rowA0 + wr * 128;
    const int gc0 = (int)rowB0 + wc * 64;
    #pragma unroll
    for (int i = 0; i < 8; ++i) {
        #pragma unroll
        for (int j = 0; j < 4; ++j) {
            int col = gc0 + j * 16 + l15;
            float bv = bias[col];
            #pragma unroll
            for (int r = 0; r < 4; ++r) {
                int row = gr0 + i * 16 + l4 * 4 + r;
                float v = fmaxf(acc[i][j][r] + bv, 0.f);
                out[(size_t)row * N + col] = f2bf(v);
            }
        }
    }
}

// ---------- GEMM3 + finale fused: M-tile 64 (512 blocks -> 2/CU) ----------
__global__ __launch_bounds__(256)
void gemm3_fused(const unsigned short* __restrict__ A,   // h2 [B,1024]
                 const unsigned short* __restrict__ Wt,  // W3s [128,1024]
                 const float* __restrict__ bias,         // [128]
                 const float* __restrict__ eps,          // [B,64]
                 float* __restrict__ act_out, float* __restrict__ logp_out, int K) {
    __shared__ char smem[32768];
    short* lA = (short*)smem;             // 64x64 shorts = 8 KB
    short* lB = (short*)(smem + 8192);    // 128x64 shorts = 16 KB
    float* fmu = (float*)smem;            // epilogue: 64x64 f32 = 16 KB
    float* fls = (float*)(smem + 16384);  // 16 KB
    const int tid  = threadIdx.x;
    const int wv   = tid >> 6, lane = tid & 63;
    const int wr   = wv >> 1,  wc   = wv & 1;     // wave: 32 rows x 64 cols
    const int l15  = lane & 15, l4  = lane >> 4;
    const size_t rowA0 = (size_t)blockIdx.x * 64;
    const unsigned short* Ab = A + rowA0 * K;
    const int arow = tid >> 3;
    const int qsw  = (tid & 7) ^ (arow & 7);

    f32x4 acc[2][4];
    #pragma unroll
    for (int i = 0; i < 2; ++i)
        #pragma unroll
        for (int j = 0; j < 4; ++j)
            acc[i][j] = f32x4{0.f, 0.f, 0.f, 0.f};

    for (int k0 = 0; k0 < K; k0 += 64) {
        #pragma unroll
        for (int c = 0; c < 2; ++c)
            g2l16(Ab + (size_t)(c * 32 + arow) * K + k0 + qsw * 8, (char*)lA + c * 4096 + tid * 16);
        #pragma unroll
        for (int c = 0; c < 4; ++c)
            g2l16(Wt + (size_t)(c * 32 + arow) * K + k0 + qsw * 8, (char*)lB + c * 4096 + tid * 16);
        __syncthreads();
        #pragma unroll
        for (int kk = 0; kk < 2; ++kk) {
            const int ch = ((kk * 4 + l4) ^ (lane & 7)) * 8;
            bf16x8 af[2], bfr[4];
            #pragma unroll
            for (int i = 0; i < 2; ++i)
                af[i] = *(const bf16x8*)(lA + (wr * 32 + i * 16 + l15) * 64 + ch);
            #pragma unroll
            for (int j = 0; j < 4; ++j)
                bfr[j] = *(const bf16x8*)(lB + (wc * 64 + j * 16 + l15) * 64 + ch);
            #pragma unroll
            for (int i = 0; i < 2; ++i)
                #pragma unroll
                for (int j = 0; j < 4; ++j)
                    acc[i][j] = __builtin_amdgcn_mfma_f32_16x16x32_bf16(af[i], bfr[j], acc[i][j], 0, 0, 0);
        }
        __syncthreads();
    }

    // Epilogue: cols 0..63 = mu (wc=0), 64..127 = log_std (wc=1), via LDS with
    // +row rotation to keep accesses ~2-way.
    {
        float* dst = wc ? fls : fmu;
        #pragma unroll
        for (int i = 0; i < 2; ++i) {
            #pragma unroll
            for (int j = 0; j < 4; ++j) {
                int c = j * 16 + l15;                 // 0..63
                float bv = bias[wc * 64 + c];
                #pragma unroll
                for (int r = 0; r < 4; ++r) {
                    int lr = wr * 32 + i * 16 + l4 * 4 + r;   // 0..63
                    dst[lr * 64 + ((c + lr) & 63)] = acc[i][j][r] + bv;
                }
            }
        }
    }
    __syncthreads();
    {
        int r = tid >> 2;                              // 0..63
        size_t grow = rowA0 + r;
        float lp = 0.f;
        #pragma unroll
        for (int t = 0; t < 16; ++t) {
            int j = (tid & 3) * 16 + t;                // 0..63
            int rot = (j + r) & 63;
            float mu = fmu[r * 64 + rot];
            float ls = fls[r * 64 + rot];
            ls = fminf(fmaxf(ls, -20.f), 2.f);
            float sd = expf(ls);
            float e  = eps[grow * 64 + j];
            float pi = fmaf(sd, e, mu);
            act_out[grow * 64 + j] = tanhf(pi);
            lp += -0.5f * e * e - ls - 0.91893853320467274178f;
            float xn = -2.f * pi;
            float sp = fmaxf(xn, 0.f) + log1pf(expf(-fabsf(xn)));
            lp -= 2.f * (0.69314718055994530942f - pi - sp);
        }
        lp += __shfl_xor(lp, 1);
        lp += __shfl_xor(lp, 2);
        if ((tid & 3) == 0) logp_out[grow] = lp;
    }
}

// ---------- launch ----------
extern "C" void kernel_launch(void* const* d_in, const int* in_sizes, int n_in,
                              void* d_out, int out_size, void* d_ws, size_t ws_size,
                              hipStream_t stream) {
    const float* obs = (const float*)d_in[0];
    const float* eps = (const float*)d_in[1];
    const float* W1  = (const float*)d_in[2];
    const float* b1  = (const float*)d_in[3];
    const float* W2  = (const float*)d_in[4];
    const float* b2  = (const float*)d_in[5];
    const float* W3  = (const float*)d_in[6];
    const float* b3  = (const float*)d_in[7];
    const int B = 32768, OBS = 512, H1 = 1024, H2 = 1024;

    char* ws = (char*)d_ws;
    unsigned short* x   = (unsigned short*)(ws);                 // 32 MB
    unsigned short* h1  = (unsigned short*)(ws + 33554432);      // 64 MB
    unsigned short* h2  = (unsigned short*)(ws + 100663296);     // 64 MB
    unsigned short* W1s = (unsigned short*)(ws + 167772160);     // 1 MB
    unsigned short* W2s = (unsigned short*)(ws + 168820736);     // 2 MB
    unsigned short* W3s = (unsigned short*)(ws + 170917888);     // 256 KB
    float*          b1q = (float*)(ws + 171180032);
    float*          b2q = (float*)(ws + 171184128);
    float*          b3q = (float*)(ws + 171188224);
    float*          scales = (float*)(ws + 171188736);
    float*          pmax   = (float*)(ws + 171189248);           // 288 floats

    wprep1<<<288, 256, 0, stream>>>(W1, W2, W3, pmax);
    wprep2<<<1, 256, 0, stream>>>(pmax, b1, b2, b3, scales, b1q, b2q, b3q);
    quant_w_all<<<832, 256, 0, stream>>>(W1, W2, W3, W1s, W2s, W3s, scales);
    cvt_bf16<<<2048, 256, 0, stream>>>(obs, x, B * OBS);

    gemm_big<3><<<dim3(8, 128), 256, 0, stream>>>(x,  W1s, b1q, h1, H1, OBS);
    gemm_big<3><<<dim3(8, 128), 256, 0, stream>>>(h1, W2s, b2q, h2, H2, H1);

    float* act_out  = (float*)d_out;
    float* logp_out = act_out + (size_t)B * 64;
    gemm3_fused<<<512, 256, 0, stream>>>(h2, W3s, b3q, eps, act_out, logp_out, H2);
}

// Round 5
// 228.085 us; speedup vs baseline: 1.5673x; 1.2208x over previous
//
#include <hip/hip_runtime.h>
#include <math.h>

typedef float f32x4 __attribute__((ext_vector_type(4)));
typedef int   v4i   __attribute__((ext_vector_type(4)));
typedef int   v8i   __attribute__((ext_vector_type(8)));

// ---------- helpers ----------
__device__ __forceinline__ void g2l16(const void* g, void* l) {
    // async global->LDS, 16B per lane; LDS dest = wave-uniform base + lane*16
    __builtin_amdgcn_global_load_lds(
        (__attribute__((address_space(1))) void*)g,
        (__attribute__((address_space(3))) void*)l,
        16, 0, 0);
}

__device__ __forceinline__ int pk8(float a, float b, int old) {
    return __builtin_amdgcn_cvt_pk_fp8_f32(a, b, old, 0);
}
__device__ __forceinline__ int pk8h(float a, float b, int old) {
    return __builtin_amdgcn_cvt_pk_fp8_f32(a, b, old, 1);
}

// ---------- quant prep: stage 1 — per-block absmax partials ----------
__global__ void wprep1(const float* __restrict__ W1, const float* __restrict__ W2,
                       const float* __restrict__ W3, float* __restrict__ pmax) {
    int blk = blockIdx.x;
    const float* w; int n, b, nb;
    if (blk < 128)      { w = W1; n = 524288;  b = blk;       nb = 128; }
    else if (blk < 256) { w = W2; n = 1048576; b = blk - 128; nb = 128; }
    else                { w = W3; n = 131072;  b = blk - 256; nb = 32;  }
    float m = 0.f;
    for (int i = b * 256 + threadIdx.x; i < n; i += nb * 256)
        m = fmaxf(m, fabsf(w[i]));
    #pragma unroll
    for (int off = 32; off; off >>= 1)
        m = fmaxf(m, __shfl_down(m, off));
    __shared__ float sm[4];
    int lane = threadIdx.x & 63, wv = threadIdx.x >> 6;
    if (lane == 0) sm[wv] = m;
    __syncthreads();
    if (threadIdx.x == 0)
        pmax[blockIdx.x] = fmaxf(fmaxf(sm[0], sm[1]), fmaxf(sm[2], sm[3]));
}

// ---------- stage 2: reduce partials -> scales; quantize biases ----------
__global__ void wprep2(const float* __restrict__ pmax,
                       const float* __restrict__ b1, const float* __restrict__ b2,
                       const float* __restrict__ b3,
                       float* __restrict__ scales,
                       float* __restrict__ b1q, float* __restrict__ b2q, float* __restrict__ b3q) {
    __shared__ float sred[3][4];
    __shared__ float ssc[3];
    int tid = threadIdx.x, lane = tid & 63, wv = tid >> 6;
    float m0 = (tid < 128) ? pmax[tid] : 0.f;
    float m1 = (tid < 128) ? pmax[128 + tid] : 0.f;
    float m2 = (tid < 32)  ? pmax[256 + tid] : 0.f;
    #pragma unroll
    for (int off = 32; off; off >>= 1) {
        m0 = fmaxf(m0, __shfl_down(m0, off));
        m1 = fmaxf(m1, __shfl_down(m1, off));
        m2 = fmaxf(m2, __shfl_down(m2, off));
    }
    if (lane == 0) { sred[0][wv] = m0; sred[1][wv] = m1; sred[2][wv] = m2; }
    __syncthreads();
    if (tid < 3) {
        float mm = fmaxf(fmaxf(sred[tid][0], sred[tid][1]), fmaxf(sred[tid][2], sred[tid][3]));
        float s = mm / 127.0f;
        scales[tid] = s; ssc[tid] = s;
    }
    __syncthreads();
    const float s_in = (float)(1.0 / 12000.0);
    float sb1 = s_in * ssc[0];
    float sb2 = sb1 * ssc[1];
    float sb3 = sb2 * ssc[2];
    for (int i = tid; i < 1024; i += 256) {
        b1q[i] = fminf(fmaxf(rintf(b1[i] / sb1), -128.f), 127.f) * sb1;
        b2q[i] = fminf(fmaxf(rintf(b2[i] / sb2), -128.f), 127.f) * sb2;
    }
    if (tid < 128) b3q[tid] = fminf(fmaxf(rintf(b3[tid] / sb3), -128.f), 127.f) * sb3;
}

// ---------- quantize all weights -> fp8 of (q * ws * 2^10) ----------
__global__ void quant_w_all(const float* __restrict__ W1, const float* __restrict__ W2,
                            const float* __restrict__ W3,
                            unsigned char* __restrict__ W1s, unsigned char* __restrict__ W2s,
                            unsigned char* __restrict__ W3s,
                            const float* __restrict__ scales) {
    int b = blockIdx.x;
    const float* w; unsigned char* o; float s; int base;
    if (b < 256)      { w = W1; o = W1s; s = scales[0]; base = b * 2048; }
    else if (b < 768) { w = W2; o = W2s; s = scales[1]; base = (b - 256) * 2048; }
    else              { w = W3; o = W3s; s = scales[2]; base = (b - 768) * 2048; }
    int i = base + threadIdx.x * 8;
    float4 a = *(const float4*)(w + i);
    float4 c = *(const float4*)(w + i + 4);
    #define QW(x) fminf(fmaxf(fminf(fmaxf(rintf((x) / s), -127.f), 127.f) * s * 1024.f, -448.f), 448.f)
    int lo = pk8(QW(a.x), QW(a.y), 0); lo = pk8h(QW(a.z), QW(a.w), lo);
    int hi = pk8(QW(c.x), QW(c.y), 0); hi = pk8h(QW(c.z), QW(c.w), hi);
    #undef QW
    *(int2*)(o + i) = make_int2(lo, hi);
}

// ---------- obs f32 -> fp8 (obs ~ N(0,1), fits e4m3 range directly) ----------
__global__ void cvt_fp8(const float* __restrict__ in, unsigned char* __restrict__ out) {
    int i = (blockIdx.x * blockDim.x + threadIdx.x) * 8;
    float4 a = *(const float4*)(in + i);
    float4 c = *(const float4*)(in + i + 4);
    int lo = pk8(a.x, a.y, 0); lo = pk8h(a.z, a.w, lo);
    int hi = pk8(c.x, c.y, 0); hi = pk8h(c.z, c.w, hi);
    *(int2*)(out + i) = make_int2(lo, hi);
}

// ---------- MX-fp8 GEMM: out_fp8 = fp8( relu(A@Wt^T * descale + bias) * osc ) ----------
// Block 256(M)x128(N), BK=128 bytes. 4 waves, wave tile 128x64 (8x4 16x16x128 MFMA).
// XOR 16B-chunk swizzle (verified 0-conflict pattern). Unit MX scales (0x7F).
template <int LGX>
__global__ __launch_bounds__(256, 2)
void gemm8(const unsigned char* __restrict__ A,   // [M,K] fp8
           const unsigned char* __restrict__ Wt,  // [N,K] fp8 (pre-scaled 2^10)
           const float* __restrict__ bias,        // [N] f32
           unsigned char* __restrict__ out,       // [M,N] fp8
           float descale, float osc, int N, int K) {
    __shared__ char smem[49152];
    char* lA = smem;            // 256x128 B = 32 KB
    char* lB = smem + 32768;    // 128x128 B = 16 KB
    const int tid  = threadIdx.x;
    const int wv   = tid >> 6, lane = tid & 63;
    const int wr   = wv >> 1,  wc   = wv & 1;     // wave: 128 rows x 64 cols
    const int l15  = lane & 15, l4  = lane >> 4;
    const int lid  = blockIdx.y * gridDim.x + blockIdx.x;
    const int xcd  = lid & 7;
    const int s    = lid >> 3;
    const int mblk = (s >> LGX) * 8 + xcd;
    const int nblk = s & ((1 << LGX) - 1);
    const size_t rowA0 = (size_t)mblk * 256;
    const size_t rowB0 = (size_t)nblk * 128;
    const unsigned char* Ab = A  + rowA0 * K;
    const unsigned char* Bb = Wt + rowB0 * K;
    const int qsw = ((tid & 7) ^ ((tid >> 3) & 7)) * 16;   // swizzled src chunk offset
    const int srow = tid >> 3;                             // 0..31

    f32x4 acc[8][4];
    #pragma unroll
    for (int i = 0; i < 8; ++i)
        #pragma unroll
        for (int j = 0; j < 4; ++j)
            acc[i][j] = f32x4{0.f, 0.f, 0.f, 0.f};

    const int p0 = ((l4 * 2) ^ (l15 & 7)) * 16;       // LDS chunk of k-lo 16B
    const int p1 = ((l4 * 2 + 1) ^ (l15 & 7)) * 16;   // LDS chunk of k-hi 16B

    for (int k0 = 0; k0 < K; k0 += 128) {
        #pragma unroll
        for (int c = 0; c < 8; ++c)
            g2l16(Ab + (size_t)(c * 32 + srow) * K + k0 + qsw, lA + c * 4096 + tid * 16);
        #pragma unroll
        for (int c = 0; c < 4; ++c)
            g2l16(Bb + (size_t)(c * 32 + srow) * K + k0 + qsw, lB + c * 4096 + tid * 16);
        __syncthreads();
        union { v8i v; v4i h[2]; } bfr[4];
        #pragma unroll
        for (int j = 0; j < 4; ++j) {
            const char* br = lB + (wc * 64 + j * 16 + l15) * 128;
            bfr[j].h[0] = *(const v4i*)(br + p0);
            bfr[j].h[1] = *(const v4i*)(br + p1);
        }
        #pragma unroll
        for (int i = 0; i < 8; ++i) {
            const char* ar = lA + (wr * 128 + i * 16 + l15) * 128;
            union { v8i v; v4i h[2]; } af;
            af.h[0] = *(const v4i*)(ar + p0);
            af.h[1] = *(const v4i*)(ar + p1);
            #pragma unroll
            for (int j = 0; j < 4; ++j)
                acc[i][j] = __builtin_amdgcn_mfma_scale_f32_16x16x128_f8f6f4(
                    af.v, bfr[j].v, acc[i][j], 0, 0, 0, 0x7F7F7F7F, 0, 0x7F7F7F7F);
        }
        __syncthreads();
    }

    // Epilogue: 4 bands of 64 rows; f32 via LDS (xor-chunk swizzled), pack fp8, dwordx4 stores
    float* fS = (float*)smem;                 // 64x128 f32 = 32 KB
    const int rr = tid >> 2;                  // 0..63
    const int cb = (tid & 3) * 32;
    float bvj[4];
    #pragma unroll
    for (int j = 0; j < 4; ++j) bvj[j] = bias[rowB0 + wc * 64 + j * 16 + l15];
    #pragma unroll
    for (int p = 0; p < 4; ++p) {
        __syncthreads();
        if (wr == (p >> 1)) {
            const int ib = (p & 1) * 4;
            #pragma unroll
            for (int ii = 0; ii < 4; ++ii) {
                #pragma unroll
                for (int j = 0; j < 4; ++j) {
                    const int col = wc * 64 + j * 16 + l15;
                    #pragma unroll
                    for (int r = 0; r < 4; ++r) {
                        const int lrow = ii * 16 + l4 * 4 + r;
                        float v = fmaxf(acc[ib + ii][j][r] * descale + bvj[j], 0.f);
                        fS[lrow * 128 + ((((col >> 4) ^ (lrow & 7)) << 4) | (col & 15))] = v;
                    }
                }
            }
        }
        __syncthreads();
        const size_t grow = rowA0 + p * 64 + rr;
        #pragma unroll
        for (int h = 0; h < 2; ++h) {
            const int c0 = cb + h * 16;
            const float* src = fS + rr * 128 + (((c0 >> 4) ^ (rr & 7)) << 4);
            v4i d;
            #pragma unroll
            for (int m = 0; m < 4; ++m) {
                float a0 = fminf(src[m * 4 + 0] * osc, 448.f);
                float a1 = fminf(src[m * 4 + 1] * osc, 448.f);
                float a2 = fminf(src[m * 4 + 2] * osc, 448.f);
                float a3 = fminf(src[m * 4 + 3] * osc, 448.f);
                d[m] = pk8h(a2, a3, pk8(a0, a1, 0));
            }
            *(v4i*)(out + grow * (size_t)N + rowB0 + c0) = d;
        }
    }
}

// ---------- GEMM3 + finale fused (fp8 inputs): 64 rows/block ----------
__global__ __launch_bounds__(256)
void gemm3_fused(const unsigned char* __restrict__ A,   // h2 [B,1024] fp8
                 const unsigned char* __restrict__ Wt,  // W3 [128,1024] fp8
                 const float* __restrict__ bias,        // [128]
                 const float* __restrict__ eps,         // [B,64]
                 float* __restrict__ act_out, float* __restrict__ logp_out,
                 float descale, int K) {
    __shared__ char smem[32768];
    char* lA = smem;             // 64x128 B = 8 KB
    char* lB = smem + 8192;      // 128x128 B = 16 KB
    float* fmu = (float*)smem;            // epilogue 64x64 f32
    float* fls = (float*)(smem + 16384);
    const int tid  = threadIdx.x;
    const int wv   = tid >> 6, lane = tid & 63;
    const int wr   = wv >> 1,  wc   = wv & 1;     // wave: 32 rows x 64 cols
    const int l15  = lane & 15, l4  = lane >> 4;
    const size_t rowA0 = (size_t)blockIdx.x * 64;
    const unsigned char* Ab = A + rowA0 * K;
    const int qsw = ((tid & 7) ^ ((tid >> 3) & 7)) * 16;
    const int srow = tid >> 3;
    const int p0 = ((l4 * 2) ^ (l15 & 7)) * 16;
    const int p1 = ((l4 * 2 + 1) ^ (l15 & 7)) * 16;

    f32x4 acc[2][4];
    #pragma unroll
    for (int i = 0; i < 2; ++i)
        #pragma unroll
        for (int j = 0; j < 4; ++j)
            acc[i][j] = f32x4{0.f, 0.f, 0.f, 0.f};

    for (int k0 = 0; k0 < K; k0 += 128) {
        #pragma unroll
        for (int c = 0; c < 2; ++c)
            g2l16(Ab + (size_t)(c * 32 + srow) * K + k0 + qsw, lA + c * 4096 + tid * 16);
        #pragma unroll
        for (int c = 0; c < 4; ++c)
            g2l16(Wt + (size_t)(c * 32 + srow) * K + k0 + qsw, lB + c * 4096 + tid * 16);
        __syncthreads();
        union { v8i v; v4i h[2]; } af[2], bfr[4];
        #pragma unroll
        for (int i = 0; i < 2; ++i) {
            const char* ar = lA + (wr * 32 + i * 16 + l15) * 128;
            af[i].h[0] = *(const v4i*)(ar + p0);
            af[i].h[1] = *(const v4i*)(ar + p1);
        }
        #pragma unroll
        for (int j = 0; j < 4; ++j) {
            const char* br = lB + (wc * 64 + j * 16 + l15) * 128;
            bfr[j].h[0] = *(const v4i*)(br + p0);
            bfr[j].h[1] = *(const v4i*)(br + p1);
        }
        #pragma unroll
        for (int i = 0; i < 2; ++i)
            #pragma unroll
            for (int j = 0; j < 4; ++j)
                acc[i][j] = __builtin_amdgcn_mfma_scale_f32_16x16x128_f8f6f4(
                    af[i].v, bfr[j].v, acc[i][j], 0, 0, 0, 0x7F7F7F7F, 0, 0x7F7F7F7F);
        __syncthreads();
    }

    // Epilogue: cols 0..63 = mu (wc=0), 64..127 = log_std (wc=1); +row rotation in LDS
    {
        float* dst = wc ? fls : fmu;
        #pragma unroll
        for (int i = 0; i < 2; ++i) {
            #pragma unroll
            for (int j = 0; j < 4; ++j) {
                int c = j * 16 + l15;                 // 0..63
                float bv = bias[wc * 64 + c];
                #pragma unroll
                for (int r = 0; r < 4; ++r) {
                    int lr = wr * 32 + i * 16 + l4 * 4 + r;   // 0..63
                    dst[lr * 64 + ((c + lr) & 63)] = acc[i][j][r] * descale + bv;
                }
            }
        }
    }
    __syncthreads();
    {
        int r = tid >> 2;                              // 0..63
        size_t grow = rowA0 + r;
        float lp = 0.f;
        #pragma unroll
        for (int t = 0; t < 16; ++t) {
            int j = (tid & 3) * 16 + t;                // 0..63
            int rot = (j + r) & 63;
            float mu = fmu[r * 64 + rot];
            float ls = fls[r * 64 + rot];
            ls = fminf(fmaxf(ls, -20.f), 2.f);
            float sd = expf(ls);
            float e  = eps[grow * 64 + j];
            float pi = fmaf(sd, e, mu);
            act_out[grow * 64 + j] = tanhf(pi);
            lp += -0.5f * e * e - ls - 0.91893853320467274178f;
            float xn = -2.f * pi;
            float sp = fmaxf(xn, 0.f) + log1pf(expf(-fabsf(xn)));
            lp -= 2.f * (0.69314718055994530942f - pi - sp);
        }
        lp += __shfl_xor(lp, 1);
        lp += __shfl_xor(lp, 2);
        if ((tid & 3) == 0) logp_out[grow] = lp;
    }
}

// ---------- launch ----------
extern "C" void kernel_launch(void* const* d_in, const int* in_sizes, int n_in,
                              void* d_out, int out_size, void* d_ws, size_t ws_size,
                              hipStream_t stream) {
    const float* obs = (const float*)d_in[0];
    const float* eps = (const float*)d_in[1];
    const float* W1  = (const float*)d_in[2];
    const float* b1  = (const float*)d_in[3];
    const float* W2  = (const float*)d_in[4];
    const float* b2  = (const float*)d_in[5];
    const float* W3  = (const float*)d_in[6];
    const float* b3  = (const float*)d_in[7];
    const int B = 32768, OBS = 512, H1 = 1024, H2 = 1024;

    char* ws = (char*)d_ws;
    unsigned char* x8  = (unsigned char*)(ws);               // 16 MB [B*512]
    unsigned char* h1  = (unsigned char*)(ws + 16777216);    // 32 MB
    unsigned char* h2  = (unsigned char*)(ws + 50331648);    // 32 MB
    unsigned char* W1s = (unsigned char*)(ws + 83886080);    // 512 KB
    unsigned char* W2s = (unsigned char*)(ws + 84410368);    // 1 MB
    unsigned char* W3s = (unsigned char*)(ws + 85458944);    // 128 KB
    float*         b1q = (float*)(ws + 85590016);
    float*         b2q = (float*)(ws + 85594112);
    float*         b3q = (float*)(ws + 85598208);
    float*         scales = (float*)(ws + 85598720);
    float*         pmax   = (float*)(ws + 85599232);

    wprep1<<<288, 256, 0, stream>>>(W1, W2, W3, pmax);
    wprep2<<<1, 256, 0, stream>>>(pmax, b1, b2, b3, scales, b1q, b2q, b3q);
    quant_w_all<<<832, 256, 0, stream>>>(W1, W2, W3, W1s, W2s, W3s, scales);
    cvt_fp8<<<8192, 256, 0, stream>>>(obs, x8);

    // scale bookkeeping (all powers of 2, exact):
    //   W* stored *2^10 ; x stored *1 (s_in^2 folded into descale1)
    //   h1 stored *2^24 ; h2 stored *2^22
    const float desc1 = (float)((1.0 / 12000.0) * (1.0 / 12000.0) / 1024.0);
    const float osc1  = 16777216.f;                   // 2^24
    const float desc2 = 1.0f / 17179869184.f;         // 2^-34
    const float osc2  = 4194304.f;                    // 2^22
    const float desc3 = (float)(1.0 / 4294967296.0);  // 2^-32

    gemm8<3><<<dim3(8, 128), 256, 0, stream>>>(x8, W1s, b1q, h1, desc1, osc1, H1, OBS);
    gemm8<3><<<dim3(8, 128), 256, 0, stream>>>(h1, W2s, b2q, h2, desc2, osc2, H2, H1);

    float* act_out  = (float*)d_out;
    float* logp_out = act_out + (size_t)B * 64;
    gemm3_fused<<<512, 256, 0, stream>>>(h2, W3s, b3q, eps, act_out, logp_out, desc3, H2);
}